// Round 1
// baseline (44.443 us; speedup 1.0000x reference)
//
#include <hip/hip_runtime.h>
#include <float.h>

#define BATCH 64
#define NROWS 8192
#define NCH   64
#define SCHNK 16                 // N-chunks per batch
#define ROWS  (NROWS / SCHNK)    // 512 rows per block
#define TOPK  9

// Branchless insert of v into descending-sorted m[0..8]; smallest falls off.
__device__ __forceinline__ void insert9(float (&m)[TOPK], float v) {
#pragma unroll
    for (int k = 0; k < TOPK; ++k) {
        float hi = fmaxf(m[k], v);
        float lo = fminf(m[k], v);
        m[k] = hi;
        v = lo;
    }
}

// Kernel 1: per-(batch,chunk) block computes top-9 per channel over its 512 rows.
// Thread t: channel group cg = t&15 (4 channels via float4), row subset ns = t>>4.
// Wave reads 1KiB contiguous per iteration (4 rows x 256B).
__global__ __launch_bounds__(256) void topk_partial(const float* __restrict__ x,
                                                    float* __restrict__ ws) {
    const int bx = blockIdx.x;
    const int b  = bx / SCHNK;
    const int s  = bx % SCHNK;
    const int t  = threadIdx.x;
    const int cg = t & 15;
    const int ns = t >> 4;

    float m[4][TOPK];
#pragma unroll
    for (int ch = 0; ch < 4; ++ch)
#pragma unroll
        for (int k = 0; k < TOPK; ++k) m[ch][k] = -FLT_MAX;

    const float4* xr = (const float4*)(x + ((size_t)b * NROWS + (size_t)s * ROWS) * NCH);
#pragma unroll 4
    for (int k = 0; k < ROWS / 16; ++k) {
        const int r = ns + k * 16;
        const float4 v = xr[r * 16 + cg];
        insert9(m[0], v.x);
        insert9(m[1], v.y);
        insert9(m[2], v.z);
        insert9(m[3], v.w);
    }

    // lists[nsub][channel][k]
    __shared__ float lists[16][NCH][TOPK];
#pragma unroll
    for (int ch = 0; ch < 4; ++ch)
#pragma unroll
        for (int k = 0; k < TOPK; ++k)
            lists[ns][4 * cg + ch][k] = m[ch][k];
    __syncthreads();

    if (t < NCH) {
        float mm[TOPK];
#pragma unroll
        for (int k = 0; k < TOPK; ++k) mm[k] = -FLT_MAX;
        for (int i = 0; i < 16; ++i)
#pragma unroll
            for (int k = 0; k < TOPK; ++k)
                insert9(mm, lists[i][t][k]);
        // ws layout: [B][SCHNK][TOPK][NCH]  (coalesced across channel lanes)
        float* w = ws + (((size_t)b * SCHNK + s) * TOPK) * NCH;
#pragma unroll
        for (int k = 0; k < TOPK; ++k) w[k * NCH + t] = mm[k];
    }
}

// Kernel 2: merge SCHNK partial top-9 lists per (b,c), mean of final top-9.
__global__ __launch_bounds__(64) void topk_final(const float* __restrict__ ws,
                                                 float* __restrict__ out) {
    const int b = blockIdx.x;
    const int c = threadIdx.x;
    float mm[TOPK];
#pragma unroll
    for (int k = 0; k < TOPK; ++k) mm[k] = -FLT_MAX;
    const float* w = ws + (size_t)b * SCHNK * TOPK * NCH;
#pragma unroll
    for (int i = 0; i < SCHNK * TOPK; ++i)
        insert9(mm, w[i * NCH + c]);
    float sum = 0.f;
#pragma unroll
    for (int k = 0; k < TOPK; ++k) sum += mm[k];
    out[b * NCH + c] = sum * (1.0f / 9.0f);
}

extern "C" void kernel_launch(void* const* d_in, const int* in_sizes, int n_in,
                              void* d_out, int out_size, void* d_ws, size_t ws_size,
                              hipStream_t stream) {
    const float* x = (const float*)d_in[0];
    float* out = (float*)d_out;
    float* ws = (float*)d_ws;   // needs B*S*9*C*4 = 2.25 MiB

    topk_partial<<<BATCH * SCHNK, 256, 0, stream>>>(x, ws);
    topk_final<<<BATCH, 64, 0, stream>>>(ws, out);
}

// Round 2
// 31.307 us; speedup vs baseline: 1.4196x; 1.4196x over previous
//
#include <hip/hip_runtime.h>
#include <float.h>

#define BATCH 64
#define NROWS 8192
#define NCH   64
#define SCHNK 16                 // N-chunks per batch
#define ROWS  (NROWS / SCHNK)    // 512 rows per block
#define TOPK  9

// Insert v into descending-sorted m[0..8], keep top-9.
// r[0] = max(m[0], v); r[k] = median(m[k-1], m[k], v)  -- all depth-1, 9 ops.
__device__ __forceinline__ void insert9(float (&m)[TOPK], float v) {
    const float r0 = fmaxf(m[0], v);
#pragma unroll
    for (int k = TOPK - 1; k >= 1; --k)
        m[k] = __builtin_amdgcn_fmed3f(m[k - 1], m[k], v);
    m[0] = r0;
}

// Kernel 1: per-(batch,chunk) block: top-9 per channel over its 512 rows.
// Stream: thread t owns 4 channels (float4, cg=t&15) x 32 rows (ns=t>>4).
// Wave reads 1 KiB contiguous per iteration.
__global__ __launch_bounds__(256) void topk_partial(const float* __restrict__ x,
                                                    float* __restrict__ ws) {
    const int bx = blockIdx.x;
    const int b  = bx >> 4;
    const int s  = bx & (SCHNK - 1);
    const int t  = threadIdx.x;
    const int cg = t & 15;
    const int ns = t >> 4;

    float m[4][TOPK];
#pragma unroll
    for (int ch = 0; ch < 4; ++ch)
#pragma unroll
        for (int k = 0; k < TOPK; ++k) m[ch][k] = -FLT_MAX;

    const float4* xr = (const float4*)(x + ((size_t)b * NROWS + (size_t)s * ROWS) * NCH);
#pragma unroll 8
    for (int k = 0; k < ROWS / 16; ++k) {
        const float4 v = xr[ns * 16 + k * 256 + cg];
        insert9(m[0], v.x);
        insert9(m[1], v.y);
        insert9(m[2], v.z);
        insert9(m[3], v.w);
    }

    __shared__ float lists[16][NCH][TOPK];   // 36 KB
    __shared__ float quarts[4][NCH][TOPK];   //  9 KB
#pragma unroll
    for (int ch = 0; ch < 4; ++ch)
#pragma unroll
        for (int k = 0; k < TOPK; ++k)
            lists[ns][4 * cg + ch][k] = m[ch][k];
    __syncthreads();

    // Stage A: 256 threads; thread (c = t&63, q = t>>6) merges 4 lists.
    {
        const int c = t & 63;
        const int q = t >> 6;
        float mm[TOPK];
#pragma unroll
        for (int k = 0; k < TOPK; ++k) mm[k] = lists[q * 4][c][k];
#pragma unroll
        for (int i = 1; i < 4; ++i)
#pragma unroll
            for (int k = 0; k < TOPK; ++k)
                insert9(mm, lists[q * 4 + i][c][k]);
#pragma unroll
        for (int k = 0; k < TOPK; ++k) quarts[q][c][k] = mm[k];
    }
    __syncthreads();

    // Stage B: 64 threads; merge the 4 quarter-lists, write partials.
    if (t < NCH) {
        float mm[TOPK];
#pragma unroll
        for (int k = 0; k < TOPK; ++k) mm[k] = quarts[0][t][k];
#pragma unroll
        for (int q = 1; q < 4; ++q)
#pragma unroll
            for (int k = 0; k < TOPK; ++k)
                insert9(mm, quarts[q][t][k]);
        // ws layout: [B][SCHNK][TOPK][NCH] (coalesced across channel lanes)
        float* w = ws + ((size_t)(b * SCHNK + s) * TOPK) * NCH;
#pragma unroll
        for (int k = 0; k < TOPK; ++k) w[k * NCH + t] = mm[k];
    }
}

// Kernel 2: merge SCHNK partial lists per (b,c); mean of final top-9.
__global__ __launch_bounds__(256) void topk_final(const float* __restrict__ ws,
                                                  float* __restrict__ out) {
    const int b = blockIdx.x;
    const int t = threadIdx.x;
    const int c = t & 63;
    const int q = t >> 6;
    __shared__ float quarts[4][NCH][TOPK];   // 9 KB

    const float* w = ws + (size_t)b * SCHNK * TOPK * NCH;
    float mm[TOPK];
#pragma unroll
    for (int k = 0; k < TOPK; ++k) mm[k] = w[((q * 4) * TOPK + k) * NCH + c];
#pragma unroll
    for (int i = 1; i < 4; ++i)
#pragma unroll
        for (int k = 0; k < TOPK; ++k)
            insert9(mm, w[((q * 4 + i) * TOPK + k) * NCH + c]);
#pragma unroll
    for (int k = 0; k < TOPK; ++k) quarts[q][c][k] = mm[k];
    __syncthreads();

    if (t < NCH) {
        float r[TOPK];
#pragma unroll
        for (int k = 0; k < TOPK; ++k) r[k] = quarts[0][t][k];
#pragma unroll
        for (int q2 = 1; q2 < 4; ++q2)
#pragma unroll
            for (int k = 0; k < TOPK; ++k)
                insert9(r, quarts[q2][t][k]);
        float sum = 0.f;
#pragma unroll
        for (int k = 0; k < TOPK; ++k) sum += r[k];
        out[b * NCH + t] = sum * (1.0f / 9.0f);
    }
}

extern "C" void kernel_launch(void* const* d_in, const int* in_sizes, int n_in,
                              void* d_out, int out_size, void* d_ws, size_t ws_size,
                              hipStream_t stream) {
    const float* x = (const float*)d_in[0];
    float* out = (float*)d_out;
    float* ws = (float*)d_ws;   // needs B*S*9*C*4 = 2.25 MiB

    topk_partial<<<BATCH * SCHNK, 256, 0, stream>>>(x, ws);
    topk_final<<<BATCH, 256, 0, stream>>>(ws, out);
}